// Round 1
// baseline (242.656 us; speedup 1.0000x reference)
//
#include <hip/hip_runtime.h>

// ---------- types ----------
typedef short  short4v __attribute__((ext_vector_type(4)));
typedef short  short8v __attribute__((ext_vector_type(8)));
typedef __bf16 bf16x8  __attribute__((ext_vector_type(8)));
typedef float  f32x4   __attribute__((ext_vector_type(4)));
typedef float  float4v __attribute__((ext_vector_type(4)));

__device__ __forceinline__ short f2bf(float f) {
  unsigned u = __builtin_bit_cast(unsigned, f);
  u += 0x7fffu + ((u >> 16) & 1u);   // RNE
  return (short)(u >> 16);
}
__device__ __forceinline__ float bf2f(short h) {
  unsigned u = ((unsigned)(unsigned short)h) << 16;
  return __builtin_bit_cast(float, u);
}

// ---------- fp32 -> bf16 convert (vectorized, n4 = n/4 groups) ----------
__global__ __launch_bounds__(256) void k_cvt(const float* __restrict__ in,
                                             short* __restrict__ out, int n4) {
  int i = blockIdx.x * 256 + threadIdx.x;
  if (i >= n4) return;
  float4v v = *reinterpret_cast<const float4v*>(in + (long)i * 4);
  short4v o;
  o[0] = f2bf(v[0]); o[1] = f2bf(v[1]); o[2] = f2bf(v[2]); o[3] = f2bf(v[3]);
  *reinterpret_cast<short4v*>(out + (long)i * 4) = o;
}

// ---------- GEMM: C[M,N] = A[M,K] * B[N,K]^T (+bias), bf16 in, fp32 acc ----------
// m97 structure: 128x128 tile, 4 waves (2x2), 4x4 16x16 fragments per wave,
// BK=64, global_load_lds width-16 staging, linear LDS.
template <bool OUT_BF16, bool TRANS_OUT, bool HAS_BIAS>
__global__ __launch_bounds__(256, 3) void k_gemm_bt(
    const short* __restrict__ A, const short* __restrict__ B,
    const float* __restrict__ bias, void* __restrict__ Cv,
    int M, int N, int K, long sA, long sB, long sC) {
  __shared__ __align__(16) short lsA[128 * 64];
  __shared__ __align__(16) short lsB[128 * 64];
  const int tid = threadIdx.x;
  const int lane = tid & 63;
  const int wid = tid >> 6;
  const int wr = wid >> 1, wc = wid & 1;
  const int fr = lane & 15, fq = lane >> 4;
  const int bm = blockIdx.x * 128, bn = blockIdx.y * 128;
  const short* Ab = A + (long)blockIdx.z * sA;
  const short* Bb = B + (long)blockIdx.z * sB;

  f32x4 acc[4][4] = {};

  for (int kt = 0; kt < K; kt += 64) {
    __syncthreads();
#pragma unroll
    for (int c = 0; c < 4; ++c) {
      int idx = c * 256 + tid;          // 16B chunk id within the 16KB tile
      int row = idx >> 3;               // tile row (0..127)
      int colh = (idx & 7) << 3;        // halfword col within BK=64
      const short* ga = Ab + (long)(bm + row) * K + kt + colh;
      const short* gb = Bb + (long)(bn + row) * K + kt + colh;
      __builtin_amdgcn_global_load_lds(
          (const __attribute__((address_space(1))) void*)ga,
          (__attribute__((address_space(3))) void*)&lsA[(long)idx * 8], 16, 0, 0);
      __builtin_amdgcn_global_load_lds(
          (const __attribute__((address_space(1))) void*)gb,
          (__attribute__((address_space(3))) void*)&lsB[(long)idx * 8], 16, 0, 0);
    }
    __syncthreads();
#pragma unroll
    for (int ks = 0; ks < 64; ks += 32) {
      bf16x8 a[4], b[4];
#pragma unroll
      for (int m = 0; m < 4; ++m)
        a[m] = __builtin_bit_cast(bf16x8,
            *reinterpret_cast<const short8v*>(&lsA[(wr * 64 + m * 16 + fr) * 64 + ks + fq * 8]));
#pragma unroll
      for (int n = 0; n < 4; ++n)
        b[n] = __builtin_bit_cast(bf16x8,
            *reinterpret_cast<const short8v*>(&lsB[(wc * 64 + n * 16 + fr) * 64 + ks + fq * 8]));
#pragma unroll
      for (int m = 0; m < 4; ++m)
#pragma unroll
        for (int n = 0; n < 4; ++n)
          acc[m][n] = __builtin_amdgcn_mfma_f32_16x16x32_bf16(a[m], b[n], acc[m][n], 0, 0, 0);
    }
  }

  const long cz = (long)blockIdx.z * sC;
#pragma unroll
  for (int n = 0; n < 4; ++n) {
    int col = bn + wc * 64 + n * 16 + fr;
    float bv = 0.f;
    if constexpr (HAS_BIAS) bv = bias[col];
#pragma unroll
    for (int m = 0; m < 4; ++m) {
      int row0 = bm + wr * 64 + m * 16 + fq * 4;
#pragma unroll
      for (int i = 0; i < 4; ++i) {
        float val = acc[m][n][i] + bv;
        long off;
        if constexpr (TRANS_OUT) off = cz + (long)col * M + (row0 + i);
        else                     off = cz + (long)(row0 + i) * N + col;
        if constexpr (OUT_BF16) ((short*)Cv)[off] = f2bf(val);
        else                    ((float*)Cv)[off] = val;
      }
    }
  }
}

// ---------- in-place row softmax on bf16 scores, rows of 2048, scale 1/32 ----------
__global__ __launch_bounds__(256) void k_softmax(short* __restrict__ S) {
  const long base = (long)blockIdx.x * 2048;
  const int t = threadIdx.x, lane = t & 63, wid = t >> 6;
  short8v raw = *reinterpret_cast<const short8v*>(S + base + t * 8);
  float x[8];
#pragma unroll
  for (int j = 0; j < 8; ++j) x[j] = bf2f(raw[j]) * 0.03125f;
  float m = x[0];
#pragma unroll
  for (int j = 1; j < 8; ++j) m = fmaxf(m, x[j]);
#pragma unroll
  for (int off = 32; off; off >>= 1) m = fmaxf(m, __shfl_xor(m, off));
  __shared__ float rmax[4], rsum[4];
  if (lane == 0) rmax[wid] = m;
  __syncthreads();
  m = fmaxf(fmaxf(rmax[0], rmax[1]), fmaxf(rmax[2], rmax[3]));
  float e[8], s = 0.f;
#pragma unroll
  for (int j = 0; j < 8; ++j) { e[j] = __expf(x[j] - m); s += e[j]; }
#pragma unroll
  for (int off = 32; off; off >>= 1) s += __shfl_xor(s, off);
  if (lane == 0) rsum[wid] = s;
  __syncthreads();
  s = rsum[0] + rsum[1] + rsum[2] + rsum[3];
  float inv = 1.0f / s;
  short8v o;
#pragma unroll
  for (int j = 0; j < 8; ++j) o[j] = f2bf(e[j] * inv);
  *reinterpret_cast<short8v*>(S + base + t * 8) = o;
}

// ---------- launcher ----------
extern "C" void kernel_launch(void* const* d_in, const int* in_sizes, int n_in,
                              void* d_out, int out_size, void* d_ws, size_t ws_size,
                              hipStream_t stream) {
  const float* x  = (const float*)d_in[0];
  const float* Wq = (const float*)d_in[1];
  const float* bq = (const float*)d_in[2];
  const float* Wk = (const float*)d_in[3];
  const float* bk = (const float*)d_in[4];
  const float* Wv = (const float*)d_in[5];
  const float* bv = (const float*)d_in[6];
  const float* Wo = (const float*)d_in[7];
  const float* bo = (const float*)d_in[8];

  // ws layout (bf16 halves unless noted): all regions fully overwritten
  // before read on every call (poison-safe).
  char* ws = (char*)d_ws;
  short* xb  = (short*)ws; ws += 8192L * 1024 * 2;   // x bf16
  short* wqb = (short*)ws; ws += 1024L * 1024 * 2;
  short* wkb = (short*)ws; ws += 1024L * 1024 * 2;
  short* wvb = (short*)ws; ws += 1024L * 1024 * 2;
  short* wob = (short*)ws; ws += 1024L * 1024 * 2;
  short* qb  = (short*)ws; ws += 8192L * 1024 * 2;   // Q
  short* kb  = (short*)ws; ws += 8192L * 1024 * 2;   // K
  short* vT  = (short*)ws; ws += 8192L * 1024 * 2;   // V transposed [b][e][s]
  short* Sc  = (short*)ws; ws += 4L * 2048 * 2048 * 2; // scores -> probs (in place)
  short* ao  = (short*)ws; ws += 8192L * 1024 * 2;   // attn output

  dim3 blk(256);
  k_cvt<<<8192, blk, 0, stream>>>(x,  xb,  2097152);
  k_cvt<<<1024, blk, 0, stream>>>(Wq, wqb, 262144);
  k_cvt<<<1024, blk, 0, stream>>>(Wk, wkb, 262144);
  k_cvt<<<1024, blk, 0, stream>>>(Wv, wvb, 262144);
  k_cvt<<<1024, blk, 0, stream>>>(Wo, wob, 262144);

  // Q = x*Wq^T + bq ; K = x*Wk^T + bk   (M=8192, N=1024, K=1024)
  k_gemm_bt<true, false, true><<<dim3(64, 8, 1), blk, 0, stream>>>(
      xb, wqb, bq, qb, 8192, 1024, 1024, 0, 0, 0);
  k_gemm_bt<true, false, true><<<dim3(64, 8, 1), blk, 0, stream>>>(
      xb, wkb, bk, kb, 8192, 1024, 1024, 0, 0, 0);
  // V, written transposed per batch: vT[b][e][s]  (batched, M=2048)
  k_gemm_bt<true, true, true><<<dim3(16, 8, 4), blk, 0, stream>>>(
      xb, wvb, bv, vT, 2048, 1024, 1024, 2048L * 1024, 0, 2048L * 1024);
  // scores[b] = Q[b] * K[b]^T  (M=N=2048, K=1024), bf16 logits
  k_gemm_bt<true, false, false><<<dim3(16, 16, 4), blk, 0, stream>>>(
      qb, kb, nullptr, Sc, 2048, 2048, 1024, 2048L * 1024, 2048L * 1024, 2048L * 2048);
  // softmax rows (scale 1/32 folded in), in place
  k_softmax<<<8192, blk, 0, stream>>>(Sc);
  // attn_out[b] = P[b] * V[b]   (A=P [2048,2048], B=vT[b] [1024,2048]^T-form)
  k_gemm_bt<true, false, false><<<dim3(16, 8, 4), blk, 0, stream>>>(
      Sc, vT, nullptr, ao, 2048, 1024, 2048, 2048L * 2048, 1024L * 2048, 2048L * 1024);
  // y = ao * Wo^T + bo -> fp32 d_out
  k_gemm_bt<false, false, true><<<dim3(64, 8, 1), blk, 0, stream>>>(
      ao, wob, bo, (float*)d_out, 8192, 1024, 1024, 0, 0, 0);
}